// Round 10
// baseline (99.070 us; speedup 1.0000x reference)
//
#include <hip/hip_runtime.h>
#include <hip/hip_bf16.h>

// NT-Xent loss, N=4096, D=256, T=0.5.
// loss = mean_r [ LSE_{c!=r}(2 z_r.z_c) - 2 z_r.z_label(r) ], z = concat(z_i,z_j) (8192x256)
// R14: R13 null -> scratch theory falsified; B was already resident. Cycle audit:
// per CU phase-pair matrix 2048 + LDS 1536 + epilogue VALU/trans 1400 + stage 550
// = 5500 ~= measured 5770 cyc -> pipes run SEQUENTIALLY (2 waves/SIMD, phase-locked,
// [MFMA block][epilogue block] order). Fix = T15 interleave with confounders removed:
//  - ping-pong acc sets (accA/accB, 2-phase parity): phase p's MFMAs into one set
//    while phase p-1's 32 exp2 (v_exp_f32) are woven 2-per-MSTEP into the stream
//    (trans/VALU fills dependent-MFMA stall slots). No pacc copies (R8's flaw).
//  - sched_group_barrier {1 DS_READ, 2 MFMA, 6 VALU} per MSTEP pins the weave (T19).
//  - rest identical to R13: named B regs, 4-deep LDS ring, stage 3 ahead, counted
//    vmcnt(8), ONE barrier/phase, setprio, diag poisoned to -1e30 before handoff.
// Budget: B 128 + accA 32 + accB 32 + misc ~30 = ~222 <= 256 (2 waves/SIMD).

typedef __bf16 bf16x8 __attribute__((ext_vector_type(8)));
typedef __bf16 bf16x4 __attribute__((ext_vector_type(4)));
typedef float  f32x16 __attribute__((ext_vector_type(16)));

#define NPAIR 4096
#define NROW  8192
#define DIM   256
#define STRIPS 16                 // 16 column strips of 512
#define RBLK  16384               // bytes per 32-row fragment block (32*256*2)
// x = dot/T * log2(e) = dot * 2*log2(e); Z pre-scaled by sqrt(2*log2 e)
#define SQSCALE 1.6986437f
#define LN2F    0.6931471805599453f
#define M2      176.0f            // fixed LSE max (log2 units); validated R5

#define EXP2F(x) __builtin_amdgcn_exp2f(x)   // raw v_exp_f32

// ---------- kernel 1: f32 -> bf16 (pre-scaled) into Z_F + positive dots + out zero ----
__global__ __launch_bounds__(256) void k_convert(const float* __restrict__ zi,
                                                 const float* __restrict__ zj,
                                                 __bf16* __restrict__ Zf,
                                                 float* __restrict__ pos,
                                                 float* __restrict__ out) {
    const int w = threadIdx.x >> 6, lane = threadIdx.x & 63;
    const int r = blockIdx.x * 4 + w;
    if (blockIdx.x == 0 && threadIdx.x == 0) out[0] = 0.0f;
    const float4 vi = *(const float4*)(zi + r * DIM + lane * 4);
    const float4 vj = *(const float4*)(zj + r * DIM + lane * 4);
    bf16x4 bi, bj;
    bi[0] = (__bf16)(vi.x * SQSCALE); bi[1] = (__bf16)(vi.y * SQSCALE);
    bi[2] = (__bf16)(vi.z * SQSCALE); bi[3] = (__bf16)(vi.w * SQSCALE);
    bj[0] = (__bf16)(vj.x * SQSCALE); bj[1] = (__bf16)(vj.y * SQSCALE);
    bj[2] = (__bf16)(vj.z * SQSCALE); bj[3] = (__bf16)(vj.w * SQSCALE);
    // lane holds k = lane*4..+3 -> chunk t = lane>>2, half = (lane>>1)&1, inner = (lane&1)*8 B
    const int t = lane >> 2, h = (lane >> 1) & 1, inner = (lane & 1) * 8;
    char* Zb = (char*)Zf;
    *(bf16x4*)(Zb + (size_t)(r >> 5) * RBLK + t * 1024 + h * 512 + (r & 31) * 16 + inner) = bi;
    const int r2 = r + NPAIR;
    *(bf16x4*)(Zb + (size_t)(r2 >> 5) * RBLK + t * 1024 + h * 512 + (r2 & 31) * 16 + inner) = bj;
    float d = vi.x * vj.x + vi.y * vj.y + vi.z * vj.z + vi.w * vj.w;
    #pragma unroll
    for (int m = 32; m >= 1; m >>= 1) d += __shfl_xor(d, m);
    if (lane == 0) pos[r] = 2.0f * d;   // natural units
}

// ---------- kernel 2: streaming fixed-max logsumexp ----------
// grid = 32 rowblocks x 16 strips = 512 blocks of 256 thr (2 blocks/CU).
// wave w owns rows R0=rb*8+2w, R1=R0+1 (64 rows, named registers).
// A staged in 4-deep LDS ring; epilogue of phase p-1 woven into phase p's MFMAs.
__global__ __launch_bounds__(256, 2) void k_lse(const __bf16* __restrict__ Zf,
                                                float* __restrict__ Lpart) {
    const int bx    = blockIdx.x;
    const int rb    = bx & 31;          // row block of 256 rows
    const int strip = bx >> 5;          // 0..15, cols strip*512 .. +512
    const int tid   = threadIdx.x;
    const int w     = tid >> 6;         // 0..3
    const int lane  = tid & 63, lm = lane & 31, half = lane >> 5;
    const int laneoff = half * 512 + lm * 16;
    const int R0 = rb * 8 + w * 2, R1 = R0 + 1;   // global 32-row block indices

    __shared__ __align__(16) char smem[65536];    // 4 x 16 KB A ring
    const char* Zb = (const char*)Zf;

    // ---- B rows -> 32 NAMED registers (128 regs, compile-time references only) ----
    const char* g0 = Zb + (size_t)R0 * RBLK + laneoff;
    const char* g1 = Zb + (size_t)R1 * RBLK + laneoff;
    #define LOADB(i) \
        bf16x8 B0_##i = *(const bf16x8*)(g0 + (i) * 1024); \
        bf16x8 B1_##i = *(const bf16x8*)(g1 + (i) * 1024);
    LOADB(0)  LOADB(1)  LOADB(2)  LOADB(3)
    LOADB(4)  LOADB(5)  LOADB(6)  LOADB(7)
    LOADB(8)  LOADB(9)  LOADB(10) LOADB(11)
    LOADB(12) LOADB(13) LOADB(14) LOADB(15)
    #undef LOADB

    const char* Acol = Zb + (size_t)strip * 16 * RBLK;   // strip's 16 col-RBLKs

    // async stage of one col-RBLK (16 KB): 256 thr x 4 x 16 B, linear LDS dest
    #define STAGE(bufsel, phidx) do {                                              \
        const char* _s = Acol + (size_t)(phidx) * RBLK + tid * 16;                 \
        char*       _d = smem + (bufsel) * 16384 + tid * 16;                       \
        _Pragma("unroll")                                                          \
        for (int _q = 0; _q < 4; _q++)                                             \
            __builtin_amdgcn_global_load_lds(                                      \
                (const __attribute__((address_space(1))) unsigned int*)(_s + _q * 4096), \
                (__attribute__((address_space(3))) unsigned int*)(_d + _q * 4096), \
                16, 0, 0);                                                         \
    } while (0)

    float l0 = 0.0f, l1 = 0.0f;

    // ping-pong accumulator sets; phase 0 "reads" accB -> init so exp2 -> 0
    f32x16 accA0 = (f32x16)(-1e30f), accA1 = (f32x16)(-1e30f);
    f32x16 accB0 = (f32x16)(-1e30f), accB1 = (f32x16)(-1e30f);

    // one MFMA K-step + 2 woven epilogue exp2 of the PREVIOUS phase (read set).
    // SGB pins the category interleave {1 ds_read, 2 MFMA, ~6 VALU} per step;
    // scheduler still free to run ds_reads ahead (counts, not instances).
    #define MSTEP(i, ...) {                                                        \
        bf16x8 a_ = *(const bf16x8*)(Ab + (i) * 1024);                             \
        WA0 = __builtin_amdgcn_mfma_f32_32x32x16_bf16(a_, B0_##i, WA0, 0, 0, 0);   \
        WA1 = __builtin_amdgcn_mfma_f32_32x32x16_bf16(a_, B1_##i, WA1, 0, 0, 0);   \
        __VA_ARGS__                                                                \
        __builtin_amdgcn_sched_group_barrier(0x100, 1, 0);                         \
        __builtin_amdgcn_sched_group_barrier(0x008, 2, 0);                         \
        __builtin_amdgcn_sched_group_barrier(0x002, 6, 0);                         \
    }

    // one phase: counted vmcnt wait, barrier, stage ph+3, then 16 MSTEPs with the
    // previous phase's 32 exp2 woven in; diag poison on the WRITTEN set at the end.
    #define PHASE_BODY(PH, PA0, PA1, PR0, PR1, WAITSTR, DO_STAGE) do {             \
        asm volatile("s_waitcnt vmcnt(" WAITSTR ")" ::: "memory");                 \
        __builtin_amdgcn_s_barrier();                                              \
        asm volatile("" ::: "memory");                                             \
        if (DO_STAGE) STAGE(((PH) + 3) & 3, (PH) + 3);                             \
        const char* Ab = smem + ((PH) & 3) * 16384 + laneoff;                      \
        f32x16 &WA0 = PA0, &WA1 = PA1;                                             \
        const f32x16 &RA0 = PR0, &RA1 = PR1;                                       \
        WA0 = (f32x16)(0.0f);                                                      \
        WA1 = (f32x16)(0.0f);                                                      \
        float e0 = 0.0f, e1 = 0.0f, e2 = 0.0f, e3 = 0.0f;                          \
        __builtin_amdgcn_s_setprio(1);                                             \
        MSTEP(0,  e0 += EXP2F(RA0[0]  - M2); e1 += EXP2F(RA0[1]  - M2);)           \
        MSTEP(1,  e0 += EXP2F(RA0[2]  - M2); e1 += EXP2F(RA0[3]  - M2);)           \
        MSTEP(2,  e0 += EXP2F(RA0[4]  - M2); e1 += EXP2F(RA0[5]  - M2);)           \
        MSTEP(3,  e0 += EXP2F(RA0[6]  - M2); e1 += EXP2F(RA0[7]  - M2);)           \
        MSTEP(4,  e0 += EXP2F(RA0[8]  - M2); e1 += EXP2F(RA0[9]  - M2);)           \
        MSTEP(5,  e0 += EXP2F(RA0[10] - M2); e1 += EXP2F(RA0[11] - M2);)           \
        MSTEP(6,  e0 += EXP2F(RA0[12] - M2); e1 += EXP2F(RA0[13] - M2);)           \
        MSTEP(7,  e0 += EXP2F(RA0[14] - M2); e1 += EXP2F(RA0[15] - M2);)           \
        MSTEP(8,  e2 += EXP2F(RA1[0]  - M2); e3 += EXP2F(RA1[1]  - M2);)           \
        MSTEP(9,  e2 += EXP2F(RA1[2]  - M2); e3 += EXP2F(RA1[3]  - M2);)           \
        MSTEP(10, e2 += EXP2F(RA1[4]  - M2); e3 += EXP2F(RA1[5]  - M2);)           \
        MSTEP(11, e2 += EXP2F(RA1[6]  - M2); e3 += EXP2F(RA1[7]  - M2);)           \
        MSTEP(12, e2 += EXP2F(RA1[8]  - M2); e3 += EXP2F(RA1[9]  - M2);)           \
        MSTEP(13, e2 += EXP2F(RA1[10] - M2); e3 += EXP2F(RA1[11] - M2);)           \
        MSTEP(14, e2 += EXP2F(RA1[12] - M2); e3 += EXP2F(RA1[13] - M2);)           \
        MSTEP(15, e2 += EXP2F(RA1[14] - M2); e3 += EXP2F(RA1[15] - M2);)           \
        __builtin_amdgcn_s_setprio(0);                                             \
        const int cb = strip * 16 + (PH);                                          \
        if (cb == R0) {   /* wave-uniform: WA0 tile holds the diagonal */          \
            _Pragma("unroll")                                                      \
            for (int rg = 0; rg < 16; rg++) {                                      \
                const int cl = (rg & 3) + 8 * (rg >> 2) + 4 * half;                \
                WA0[rg] = (cl == lm) ? -1e30f : WA0[rg];                           \
            }                                                                      \
        }                                                                          \
        if (cb == R1) {                                                            \
            _Pragma("unroll")                                                      \
            for (int rg = 0; rg < 16; rg++) {                                      \
                const int cl = (rg & 3) + 8 * (rg >> 2) + 4 * half;                \
                WA1[rg] = (cl == lm) ? -1e30f : WA1[rg];                           \
            }                                                                      \
        }                                                                          \
        l0 += e0 + e1;                                                             \
        l1 += e2 + e3;                                                             \
    } while (0)

    // prologue: 3 stages in flight (12 loads/thread)
    STAGE(0, 0);
    STAGE(1, 1);
    STAGE(2, 2);

    // pairs: even phase writes accA reads accB; odd writes accB reads accA
    for (int ph = 0; ph < 12; ph += 2) {
        PHASE_BODY(ph,     accA0, accA1, accB0, accB1, "8", 1);
        PHASE_BODY(ph + 1, accB0, accB1, accA0, accA1, "8", 1);
    }
    PHASE_BODY(12, accA0, accA1, accB0, accB1, "8", 1);   // stages 15
    PHASE_BODY(13, accB0, accB1, accA0, accA1, "8", 0);
    PHASE_BODY(14, accA0, accA1, accB0, accB1, "4", 0);
    PHASE_BODY(15, accB0, accB1, accA0, accA1, "0", 0);

    #undef PHASE_BODY
    #undef MSTEP
    #undef STAGE

    // drain: epilogue of phase 15 (written into accB, already diag-poisoned)
    #pragma unroll
    for (int rg = 0; rg < 16; rg++) {
        l0 += EXP2F(accB0[rg] - M2);
        l1 += EXP2F(accB1[rg] - M2);
    }

    // merge k-halves (lane <-> lane^32: same row, disjoint col subsets) by ADD
    l0 += __shfl_xor(l0, 32);
    l1 += __shfl_xor(l1, 32);
    if (half == 0) {
        Lpart[strip * NROW + R0 * 32 + lm] = l0;
        Lpart[strip * NROW + R1 * 32 + lm] = l1;
    }
}

// ---------- kernel 3: merge strips, per-row loss, atomic mean ----------
__global__ __launch_bounds__(256) void k_final(const float* __restrict__ Lpart,
                                               const float* __restrict__ pos,
                                               float* __restrict__ out) {
    __shared__ float red[256];
    const int t = threadIdx.x;
    const int r = blockIdx.x * 256 + t;
    float l = 0.0f;
    #pragma unroll
    for (int s = 0; s < STRIPS; s++) l += Lpart[s * NROW + r];
    const float lse = (M2 + __builtin_log2f(l)) * LN2F;   // natural-log LSE
    red[t] = lse - pos[r & (NPAIR - 1)];
    __syncthreads();
    for (int ofs = 128; ofs > 0; ofs >>= 1) {
        if (t < ofs) red[t] += red[t + ofs];
        __syncthreads();
    }
    if (t == 0) atomicAdd(out, red[0] / (float)NROW);
}

extern "C" void kernel_launch(void* const* d_in, const int* in_sizes, int n_in,
                              void* d_out, int out_size, void* d_ws, size_t ws_size,
                              hipStream_t stream) {
    const float* zi = (const float*)d_in[0];
    const float* zj = (const float*)d_in[1];
    __bf16* Zf   = (__bf16*)d_ws;                       // 4 MB fragment-ready
    float* pos   = (float*)((char*)d_ws + (size_t)NROW * DIM * 2);
    float* Lpart = pos + NPAIR;                         // 16 x 8192 floats

    k_convert<<<NPAIR / 4, 256, 0, stream>>>(zi, zj, Zf, pos, (float*)d_out);
    k_lse<<<32 * STRIPS, 256, 0, stream>>>(Zf, Lpart);
    k_final<<<NROW / 256, 256, 0, stream>>>(Lpart, pos, (float*)d_out);
}

// Round 11
// 94.197 us; speedup vs baseline: 1.0517x; 1.0517x over previous
//
#include <hip/hip_runtime.h>
#include <hip/hip_bf16.h>

// NT-Xent loss, N=4096, D=256, T=0.5.
// loss = mean_r [ LSE_{c!=r}(2 z_r.z_c) - 2 z_r.z_label(r) ], z = concat(z_i,z_j) (8192x256)
// R15 = R13 + co-block ANTI-PHASE stagger. R14 spilled (WRITE_SIZE 18MB = scratch).
// R13 audit: 38.5us = 890 TF = the m97-structure 36% ceiling. Cycle model: the two
// co-resident blocks (2 blocks/CU) launch together with identical data-independent
// phase durations -> lockstep: both hit the CU-shared LDS unit (~770cy) and matrix
// pipe (~1024cy) at the same instants -> serial 5770 cyc/phase (measured). Fix:
// odd-parity blocks s_sleep(45) (~2880cy = half phase) once before the phase loop
// -> persistent anti-phase: B's ds+MFMA slots into A's epilogue/stage/barrier
// window. Parity (bx^(bx>>8))&1 differs under either co-residency pairing.
// Everything else byte-identical to R13 (named B regs, 4-deep ring, stage 3 ahead,
// counted vmcnt(8), ONE barrier/phase, setprio, v_exp_f32, diag poison).

typedef __bf16 bf16x8 __attribute__((ext_vector_type(8)));
typedef __bf16 bf16x4 __attribute__((ext_vector_type(4)));
typedef float  f32x16 __attribute__((ext_vector_type(16)));

#define NPAIR 4096
#define NROW  8192
#define DIM   256
#define STRIPS 16                 // 16 column strips of 512
#define RBLK  16384               // bytes per 32-row fragment block (32*256*2)
// x = dot/T * log2(e) = dot * 2*log2(e); Z pre-scaled by sqrt(2*log2 e)
#define SQSCALE 1.6986437f
#define LN2F    0.6931471805599453f
#define M2      176.0f            // fixed LSE max (log2 units); validated R5

#define EXP2F(x) __builtin_amdgcn_exp2f(x)   // raw v_exp_f32

// ---------- kernel 1: f32 -> bf16 (pre-scaled) into Z_F + positive dots + out zero ----
__global__ __launch_bounds__(256) void k_convert(const float* __restrict__ zi,
                                                 const float* __restrict__ zj,
                                                 __bf16* __restrict__ Zf,
                                                 float* __restrict__ pos,
                                                 float* __restrict__ out) {
    const int w = threadIdx.x >> 6, lane = threadIdx.x & 63;
    const int r = blockIdx.x * 4 + w;
    if (blockIdx.x == 0 && threadIdx.x == 0) out[0] = 0.0f;
    const float4 vi = *(const float4*)(zi + r * DIM + lane * 4);
    const float4 vj = *(const float4*)(zj + r * DIM + lane * 4);
    bf16x4 bi, bj;
    bi[0] = (__bf16)(vi.x * SQSCALE); bi[1] = (__bf16)(vi.y * SQSCALE);
    bi[2] = (__bf16)(vi.z * SQSCALE); bi[3] = (__bf16)(vi.w * SQSCALE);
    bj[0] = (__bf16)(vj.x * SQSCALE); bj[1] = (__bf16)(vj.y * SQSCALE);
    bj[2] = (__bf16)(vj.z * SQSCALE); bj[3] = (__bf16)(vj.w * SQSCALE);
    // lane holds k = lane*4..+3 -> chunk t = lane>>2, half = (lane>>1)&1, inner = (lane&1)*8 B
    const int t = lane >> 2, h = (lane >> 1) & 1, inner = (lane & 1) * 8;
    char* Zb = (char*)Zf;
    *(bf16x4*)(Zb + (size_t)(r >> 5) * RBLK + t * 1024 + h * 512 + (r & 31) * 16 + inner) = bi;
    const int r2 = r + NPAIR;
    *(bf16x4*)(Zb + (size_t)(r2 >> 5) * RBLK + t * 1024 + h * 512 + (r2 & 31) * 16 + inner) = bj;
    float d = vi.x * vj.x + vi.y * vj.y + vi.z * vj.z + vi.w * vj.w;
    #pragma unroll
    for (int m = 32; m >= 1; m >>= 1) d += __shfl_xor(d, m);
    if (lane == 0) pos[r] = 2.0f * d;   // natural units
}

// ---------- kernel 2: streaming fixed-max logsumexp ----------
// grid = 32 rowblocks x 16 strips = 512 blocks of 256 thr (2 blocks/CU).
// wave w owns rows R0=rb*8+2w, R1=R0+1 (64 rows, in NAMED registers).
// A staged in 4-deep LDS ring. Odd-parity blocks anti-phased by s_sleep.
__global__ __launch_bounds__(256, 2) void k_lse(const __bf16* __restrict__ Zf,
                                                float* __restrict__ Lpart) {
    const int bx    = blockIdx.x;
    const int rb    = bx & 31;          // row block of 256 rows
    const int strip = bx >> 5;          // 0..15, cols strip*512 .. +512
    const int tid   = threadIdx.x;
    const int w     = tid >> 6;         // 0..3
    const int lane  = tid & 63, lm = lane & 31, half = lane >> 5;
    const int laneoff = half * 512 + lm * 16;
    const int R0 = rb * 8 + w * 2, R1 = R0 + 1;   // global 32-row block indices

    __shared__ __align__(16) char smem[65536];    // 4 x 16 KB A ring
    const char* Zb = (const char*)Zf;

    // ---- B rows -> 32 NAMED registers (128 VGPR, compile-time references only) ----
    const char* g0 = Zb + (size_t)R0 * RBLK + laneoff;
    const char* g1 = Zb + (size_t)R1 * RBLK + laneoff;
    #define LOADB(i) \
        bf16x8 B0_##i = *(const bf16x8*)(g0 + (i) * 1024); \
        bf16x8 B1_##i = *(const bf16x8*)(g1 + (i) * 1024);
    LOADB(0)  LOADB(1)  LOADB(2)  LOADB(3)
    LOADB(4)  LOADB(5)  LOADB(6)  LOADB(7)
    LOADB(8)  LOADB(9)  LOADB(10) LOADB(11)
    LOADB(12) LOADB(13) LOADB(14) LOADB(15)
    #undef LOADB

    const char* Acol = Zb + (size_t)strip * 16 * RBLK;   // strip's 16 col-RBLKs

    // async stage of one col-RBLK (16 KB): 256 thr x 4 x 16 B, linear LDS dest
    #define STAGE(bufsel, phidx) do {                                              \
        const char* _s = Acol + (size_t)(phidx) * RBLK + tid * 16;                 \
        char*       _d = smem + (bufsel) * 16384 + tid * 16;                       \
        _Pragma("unroll")                                                          \
        for (int _q = 0; _q < 4; _q++)                                             \
            __builtin_amdgcn_global_load_lds(                                      \
                (const __attribute__((address_space(1))) unsigned int*)(_s + _q * 4096), \
                (__attribute__((address_space(3))) unsigned int*)(_d + _q * 4096), \
                16, 0, 0);                                                         \
    } while (0)

    float l0 = 0.0f, l1 = 0.0f;

    // one MFMA K-step: a-frag from LDS (compile-time offset), named B refs.
    #define MSTEP(i) {                                                             \
        bf16x8 a_ = *(const bf16x8*)(Ab + (i) * 1024);                             \
        acc0 = __builtin_amdgcn_mfma_f32_32x32x16_bf16(a_, B0_##i, acc0, 0, 0, 0); \
        acc1 = __builtin_amdgcn_mfma_f32_32x32x16_bf16(a_, B1_##i, acc1, 0, 0, 0); \
    }

    // one phase: wait own stage-ph loads (counted), barrier, issue stage ph+3 into
    // the just-freed buffer, 32 MFMA (fully named), diag poison, v_exp_f32 epilogue.
    #define PHASE_BODY(PH, WAITSTR, DO_STAGE) do {                                 \
        asm volatile("s_waitcnt vmcnt(" WAITSTR ")" ::: "memory");                 \
        __builtin_amdgcn_s_barrier();                                              \
        asm volatile("" ::: "memory");                                             \
        if (DO_STAGE) STAGE(((PH) + 3) & 3, (PH) + 3);                             \
        const char* Ab = smem + ((PH) & 3) * 16384 + laneoff;                      \
        f32x16 acc0 = (f32x16)(0.0f);                                              \
        f32x16 acc1 = (f32x16)(0.0f);                                              \
        __builtin_amdgcn_s_setprio(1);                                             \
        MSTEP(0)  MSTEP(1)  MSTEP(2)  MSTEP(3)                                     \
        MSTEP(4)  MSTEP(5)  MSTEP(6)  MSTEP(7)                                     \
        MSTEP(8)  MSTEP(9)  MSTEP(10) MSTEP(11)                                    \
        MSTEP(12) MSTEP(13) MSTEP(14) MSTEP(15)                                    \
        __builtin_amdgcn_s_setprio(0);                                             \
        const int cb = strip * 16 + (PH);                                          \
        if (cb == R0) {   /* wave-uniform: acc0 tile holds the diagonal */         \
            _Pragma("unroll")                                                      \
            for (int rg = 0; rg < 16; rg++) {                                      \
                const int cl = (rg & 3) + 8 * (rg >> 2) + 4 * half;                \
                acc0[rg] = (cl == lm) ? -1e30f : acc0[rg];                         \
            }                                                                      \
        }                                                                          \
        if (cb == R1) {                                                            \
            _Pragma("unroll")                                                      \
            for (int rg = 0; rg < 16; rg++) {                                      \
                const int cl = (rg & 3) + 8 * (rg >> 2) + 4 * half;                \
                acc1[rg] = (cl == lm) ? -1e30f : acc1[rg];                         \
            }                                                                      \
        }                                                                          \
        float p0 = 0.0f, p1 = 0.0f, q0 = 0.0f, q1 = 0.0f;                          \
        _Pragma("unroll")                                                          \
        for (int rg = 0; rg < 16; rg += 2) {                                       \
            p0 += EXP2F(acc0[rg]     - M2);                                        \
            p1 += EXP2F(acc0[rg + 1] - M2);                                        \
            q0 += EXP2F(acc1[rg]     - M2);                                        \
            q1 += EXP2F(acc1[rg + 1] - M2);                                        \
        }                                                                          \
        l0 += p0 + p1;                                                             \
        l1 += q0 + q1;                                                             \
    } while (0)

    // prologue: 3 stages in flight (12 loads/thread)
    STAGE(0, 0);
    STAGE(1, 1);
    STAGE(2, 2);

    // ANTI-PHASE: odd-parity blocks sleep ~2880 cyc (half a phase) so co-resident
    // block pairs interleave their LDS/MFMA bursts with the partner's epilogue.
    // Parity differs for pairings (2k,2k+1) and (k,k+256). Timing-only; no
    // correctness impact (stages already issued; vmcnt unaffected by s_sleep).
    if ((bx ^ (bx >> 8)) & 1) __builtin_amdgcn_s_sleep(45);

    for (int ph = 0; ph < 14; ph++) {
        PHASE_BODY(ph, "8", ph < 13);   // steady state: keep 2 stages (8 loads) flying
    }
    PHASE_BODY(14, "4", 0);
    PHASE_BODY(15, "0", 0);

    #undef PHASE_BODY
    #undef MSTEP
    #undef STAGE

    // merge k-halves (lane <-> lane^32: same row, disjoint col subsets) by ADD
    l0 += __shfl_xor(l0, 32);
    l1 += __shfl_xor(l1, 32);
    if (half == 0) {
        Lpart[strip * NROW + R0 * 32 + lm] = l0;
        Lpart[strip * NROW + R1 * 32 + lm] = l1;
    }
}

// ---------- kernel 3: merge strips, per-row loss, atomic mean ----------
__global__ __launch_bounds__(256) void k_final(const float* __restrict__ Lpart,
                                               const float* __restrict__ pos,
                                               float* __restrict__ out) {
    __shared__ float red[256];
    const int t = threadIdx.x;
    const int r = blockIdx.x * 256 + t;
    float l = 0.0f;
    #pragma unroll
    for (int s = 0; s < STRIPS; s++) l += Lpart[s * NROW + r];
    const float lse = (M2 + __builtin_log2f(l)) * LN2F;   // natural-log LSE
    red[t] = lse - pos[r & (NPAIR - 1)];
    __syncthreads();
    for (int ofs = 128; ofs > 0; ofs >>= 1) {
        if (t < ofs) red[t] += red[t + ofs];
        __syncthreads();
    }
    if (t == 0) atomicAdd(out, red[0] / (float)NROW);
}

extern "C" void kernel_launch(void* const* d_in, const int* in_sizes, int n_in,
                              void* d_out, int out_size, void* d_ws, size_t ws_size,
                              hipStream_t stream) {
    const float* zi = (const float*)d_in[0];
    const float* zj = (const float*)d_in[1];
    __bf16* Zf   = (__bf16*)d_ws;                       // 4 MB fragment-ready
    float* pos   = (float*)((char*)d_ws + (size_t)NROW * DIM * 2);
    float* Lpart = pos + NPAIR;                         // 16 x 8192 floats

    k_convert<<<NPAIR / 4, 256, 0, stream>>>(zi, zj, Zf, pos, (float*)d_out);
    k_lse<<<32 * STRIPS, 256, 0, stream>>>(Zf, Lpart);
    k_final<<<NROW / 256, 256, 0, stream>>>(Lpart, pos, (float*)d_out);
}